// Round 1
// baseline (474.633 us; speedup 1.0000x reference)
//
#include <hip/hip_runtime.h>
#include <hip/hip_bf16.h>

// PINN fused forward+jvp^2 via split-fp16 MFMA.
// R11: BS 16->32, 1024 threads, 1 block/CU (133KB LDS). Each wave loads an
// A-fragment ONCE and applies it to TWO 16-sample groups resident in LDS:
// per-sample weight L2 traffic and per-sample barrier count both halve.
// NWACT/NMT retuned so per-sample ds_read traffic stays at R10 levels
// (L2/L4: 7 waves x NMT=2; L3: 16 waves x NMT=2). L5 splits 14 waves as
// (group = wv/7). Everything else (packed fragment-ready weights, split-fp16
// 3-product v / plain-fp16 d,dd, fp32 vector tail) unchanged from R10.

#define NSAMP 65536
#define Q     100
#define DTC   0.8f
#define BS    32
#define THREADS 1024
#define STR   520          // LDS plane stride (halves)

typedef _Float16 h8 __attribute__((ext_vector_type(8)));
typedef _Float16 h4 __attribute__((ext_vector_type(4)));
typedef float    f4 __attribute__((ext_vector_type(4)));

// ---- packed fragment-ready weight geometry (halves) ----
// per layer: MT * KT * 512 halves (frag = 64 lanes x 8 halves)
// L1: MT=4,  KT=1  ->   2048
// L2: MT=14, KT=2  ->  14336
// L3: MT=32, KT=7  -> 114688
// L4: MT=14, KT=16 -> 114688
// L5: MT=7,  KT=7  ->  25088
#define SW 270848
#define C1 0
#define C2 2048
#define C3 16384
#define C4 131072
#define C5 245760
#define BP1 0
#define BP2 64
#define BP3 288
#define BP4 800
#define BP5 1024
#define BPTOT 1136
#define WS_BIAS_BYTE_OFF (SW*2*2)

__device__ __forceinline__ float fast_tanh(float z) {
    float az = fabsf(z);
    float e  = __expf(-2.0f * az);
    float r  = __builtin_amdgcn_rcpf(1.0f + e);
    float t  = (1.0f - e) * r;
    return copysignf(t, z);
}

struct Split { _Float16 hi, lo; };
__device__ __forceinline__ Split split16(float v) {
    Split s;
    s.hi = (_Float16)v;
    s.lo = (_Float16)(v - (float)s.hi);
    return s;
}

// ---------------- pre-pass: split/pad/PACK weights + biases into d_ws ----------------
__global__ __launch_bounds__(256) void prepass(
    const float* __restrict__ W1, const float* __restrict__ b1,
    const float* __restrict__ W2, const float* __restrict__ b2,
    const float* __restrict__ W3, const float* __restrict__ b3,
    const float* __restrict__ W4, const float* __restrict__ b4,
    const float* __restrict__ W5, const float* __restrict__ b5,
    _Float16* __restrict__ whi, float* __restrict__ biasP)
{
    int idx = blockIdx.x * 256 + threadIdx.x;
    _Float16* wlo = whi + SW;
    if (idx < SW) {
        int base, KT, K, FOUT; const float* W;
        if      (idx < C2) { base=C1; KT=1;  K=20;  FOUT=50;  W=W1; }
        else if (idx < C3) { base=C2; KT=2;  K=50;  FOUT=200; W=W2; }
        else if (idx < C4) { base=C3; KT=7;  K=200; FOUT=500; W=W3; }
        else if (idx < C5) { base=C4; KT=16; K=500; FOUT=200; W=W4; }
        else               { base=C5; KT=7;  K=200; FOUT=100; W=W5; }
        int r    = idx - base;
        int frag = r >> 9;
        int f    = r & 511;
        int lane = f >> 3;
        int e    = f & 7;
        int colS = lane & 15;
        int kg   = lane >> 4;
        int mt   = frag / KT;
        int kt   = frag - mt * KT;
        int o = mt * 16 + colS;
        int k = kt * 32 + kg * 8 + e;
        float v = (o < FOUT && k < K) ? W[o * K + k] : 0.f;
        Split sp = split16(v);
        whi[idx] = sp.hi; wlo[idx] = sp.lo;
    } else if (idx < SW + BPTOT) {
        int b = idx - SW;
        const float* src; int FOUT; int o;
        if      (b < BP2)  { src=b1; FOUT=50;  o=b;        }
        else if (b < BP3)  { src=b2; FOUT=200; o=b-BP2;    }
        else if (b < BP4)  { src=b3; FOUT=500; o=b-BP3;    }
        else if (b < BP5)  { src=b4; FOUT=200; o=b-BP4;    }
        else               { src=b5; FOUT=100; o=b-BP5;    }
        biasP[b] = (o < FOUT) ? src[o] : 0.f;
    }
}

// ---------------- one MFMA layer, two 16-sample groups per A-fragment ----------------
// Planes (LDS, stride STR halves, 32 sample-columns): vhi, vlo, dhi, ddh.
// B-frag group g: lane l -> col = (l&15) + 16*g, k0 = (l>>4)*8 + kt*32.
// A-frag: PACKED: base + (mt*KT + kt)*512 + lane*8 -> coalesced 1KB load, used
// for BOTH groups (the R11 reuse).
// C/D: col(lane&15)=sample-in-group, row((lane>>4)*4+reg)=output neuron.
template<int KP, int MTILES, int NMT, int NWACT, int FOUT, bool TANH>
__device__ __forceinline__ void layer_mfma(
    const _Float16* __restrict__ whi, const _Float16* __restrict__ wlo,
    int wcoff, const float* __restrict__ biasP,
    _Float16* vhi, _Float16* vlo, _Float16* dhi, _Float16* ddh,
    int lane, int wv)
{
    constexpr int KT = KP / 32;
    const int colS = lane & 15;
    const int kg   = lane >> 4;
    const bool act = (wv < NWACT);

    f4 accv[NMT][2], accd[NMT][2], accdd[NMT][2];

    if (act) {
#pragma unroll
        for (int i = 0; i < NMT; ++i)
#pragma unroll
            for (int g = 0; g < 2; ++g) {
                accv[i][g]  = (f4){0.f, 0.f, 0.f, 0.f};
                accd[i][g]  = (f4){0.f, 0.f, 0.f, 0.f};
                accdd[i][g] = (f4){0.f, 0.f, 0.f, 0.f};
            }

        const int boff0 = colS * STR + kg * 8;
        const int boff1 = boff0 + 16 * STR;

        unsigned woff[NMT];
#pragma unroll
        for (int i = 0; i < NMT; ++i) {
            int mt  = wv + NWACT * i;
            int mtc = mt < MTILES ? mt : MTILES - 1;
            woff[i] = (unsigned)(wcoff + (mtc * KT) * 512 + lane * 8);
        }

#pragma unroll 2
        for (int kt = 0; kt < KT; ++kt) {
            const int kb  = kt * 32;        // LDS k offset (halves)
            const int kwb = kt * 512;       // packed weight offset (halves)
            h8 B0vh = *(const h8*)(vhi + boff0 + kb);
            h8 B0vl = *(const h8*)(vlo + boff0 + kb);
            h8 B0dh = *(const h8*)(dhi + boff0 + kb);
            h8 B0dd = *(const h8*)(ddh + boff0 + kb);
            h8 B1vh = *(const h8*)(vhi + boff1 + kb);
            h8 B1vl = *(const h8*)(vlo + boff1 + kb);
            h8 B1dh = *(const h8*)(dhi + boff1 + kb);
            h8 B1dd = *(const h8*)(ddh + boff1 + kb);
#pragma unroll
            for (int i = 0; i < NMT; ++i) {
                if (wv + NWACT * i < MTILES) {
                    h8 Ahi = *(const h8*)(whi + woff[i] + kwb);
                    h8 Alo = *(const h8*)(wlo + woff[i] + kwb);
                    accv[i][0]  = __builtin_amdgcn_mfma_f32_16x16x32_f16(Ahi, B0vh, accv[i][0],  0, 0, 0);
                    accv[i][0]  = __builtin_amdgcn_mfma_f32_16x16x32_f16(Ahi, B0vl, accv[i][0],  0, 0, 0);
                    accv[i][0]  = __builtin_amdgcn_mfma_f32_16x16x32_f16(Alo, B0vh, accv[i][0],  0, 0, 0);
                    accd[i][0]  = __builtin_amdgcn_mfma_f32_16x16x32_f16(Ahi, B0dh, accd[i][0],  0, 0, 0);
                    accdd[i][0] = __builtin_amdgcn_mfma_f32_16x16x32_f16(Ahi, B0dd, accdd[i][0], 0, 0, 0);
                    accv[i][1]  = __builtin_amdgcn_mfma_f32_16x16x32_f16(Ahi, B1vh, accv[i][1],  0, 0, 0);
                    accv[i][1]  = __builtin_amdgcn_mfma_f32_16x16x32_f16(Ahi, B1vl, accv[i][1],  0, 0, 0);
                    accv[i][1]  = __builtin_amdgcn_mfma_f32_16x16x32_f16(Alo, B1vh, accv[i][1],  0, 0, 0);
                    accd[i][1]  = __builtin_amdgcn_mfma_f32_16x16x32_f16(Ahi, B1dh, accd[i][1],  0, 0, 0);
                    accdd[i][1] = __builtin_amdgcn_mfma_f32_16x16x32_f16(Ahi, B1dd, accdd[i][1], 0, 0, 0);
                }
            }
        }
    }
    __syncthreads();   // all reads of planes complete before in-place overwrite

    if (act) {
#pragma unroll
        for (int i = 0; i < NMT; ++i) {
            int mt = wv + NWACT * i;
            if (mt < MTILES) {
                int o0 = mt * 16 + kg * 4;
                f4 bi = *(const f4*)(biasP + o0);
#pragma unroll
                for (int g = 0; g < 2; ++g) {
                    h4 pvh, pvl, pdh, pdd;
#pragma unroll
                    for (int r = 0; r < 4; ++r) {
                        float zv  = accv[i][g][r] + bi[r];
                        float zd  = accd[i][g][r];
                        float zdd = accdd[i][g][r];
                        float ov, od, odd;
                        if constexpr (TANH) {
                            float t  = fast_tanh(zv);
                            float s2 = 1.0f - t * t;
                            ov  = t;
                            od  = s2 * zd;
                            odd = s2 * zdd - 2.0f * t * s2 * zd * zd;
                        } else {
                            ov = zv; od = zd; odd = zdd;
                        }
                        if (o0 + r >= FOUT) { ov = 0.f; od = 0.f; odd = 0.f; }
                        Split sv = split16(ov);
                        pvh[r] = sv.hi; pvl[r] = sv.lo;
                        pdh[r] = (_Float16)od;
                        pdd[r] = (_Float16)odd;
                    }
                    int off = (colS + 16 * g) * STR + o0;
                    *(h4*)(vhi + off) = pvh;
                    *(h4*)(vlo + off) = pvl;
                    *(h4*)(dhi + off) = pdh;
                    *(h4*)(ddh + off) = pdd;
                }
            }
        }
    }
    __syncthreads();
}

// ---------------- main fused kernel ----------------
__global__ __launch_bounds__(THREADS, 4) void pinn_mfma(
    const float* __restrict__ W0, const float* __restrict__ b0,
    const float* __restrict__ x,  const float* __restrict__ A,
    const float* __restrict__ bvec,
    const _Float16* __restrict__ whi, const float* __restrict__ biasP,
    float* __restrict__ out)
{
    __shared__ __align__(16) _Float16 smem[4 * BS * STR];   // 133,120 B
    __shared__ float xs[BS];

    _Float16* vhi = smem + 0 * BS * STR;
    _Float16* vlo = smem + 1 * BS * STR;
    _Float16* dhi = smem + 2 * BS * STR;
    _Float16* ddh = smem + 3 * BS * STR;
    // Fm/Um overlay the plane space after the last MFMA layer's barrier
    float* Fm = (float*)smem;              // 32 x 104 floats
    float* Um = Fm + BS * 104;

    const int tid  = threadIdx.x;
    const int bid  = blockIdx.x;
    const int lane = tid & 63;
    const int wv   = tid >> 6;
    const _Float16* wlo = whi + SW;

    if (tid < BS) xs[tid] = x[bid * BS + tid];
    __syncthreads();

    // ---- layer 0: 1 -> 20, write padded-K (32) input planes, 32 samples ----
    {
        int s = tid >> 5;       // 0..31
        int k = tid & 31;       // 0..31
        float v0 = 0.f, v1 = 0.f, v2 = 0.f;
        if (k < 20) {
            float w  = W0[k];
            float z  = w * xs[s] + b0[k];
            float t  = fast_tanh(z);
            float s2 = 1.0f - t * t;
            v0 = t; v1 = s2 * w; v2 = -2.0f * t * s2 * w * w;
        }
        Split s0 = split16(v0);
        int off = s * STR + k;
        vhi[off] = s0.hi;           vlo[off] = s0.lo;
        dhi[off] = (_Float16)v1;    ddh[off] = (_Float16)v2;
    }
    __syncthreads();

    //          KP   MT NMT NWA FOUT
    layer_mfma< 32,  4, 1,  4,  50, true>(whi, wlo, C1, biasP + BP1, vhi, vlo, dhi, ddh, lane, wv);
    layer_mfma< 64, 14, 2,  7, 200, true>(whi, wlo, C2, biasP + BP2, vhi, vlo, dhi, ddh, lane, wv);
    layer_mfma<224, 32, 2, 16, 500, true>(whi, wlo, C3, biasP + BP3, vhi, vlo, dhi, ddh, lane, wv);
    layer_mfma<512, 14, 2,  7, 200, true>(whi, wlo, C4, biasP + BP4, vhi, vlo, dhi, ddh, lane, wv);

    // ---- layer 5: 200 -> 100 linear, epilogue -> U, Uxx, F (overlay) ----
    // 14 waves: waves 0..6 handle sample group 0, waves 7..13 group 1.
    {
        constexpr int KT = 7;
        const int colS = lane & 15;
        const int kg   = lane >> 4;
        const bool act = (wv < 14);
        const int g    = (wv >= 7) ? 1 : 0;
        const int mtw  = wv - 7 * g;
        f4 av = (f4){0.f,0.f,0.f,0.f}, ad = av, add = av;
        if (act) {
            const int boff = (colS + 16 * g) * STR + kg * 8;
            const unsigned w5off = (unsigned)(C5 + (mtw * KT) * 512 + lane * 8);
#pragma unroll 2
            for (int kt = 0; kt < KT; ++kt) {
                const int kb  = kt * 32;
                const int kwb = kt * 512;
                h8 Bvh = *(const h8*)(vhi + boff + kb);
                h8 Bvl = *(const h8*)(vlo + boff + kb);
                h8 Bdh = *(const h8*)(dhi + boff + kb);
                h8 Bdd = *(const h8*)(ddh + boff + kb);
                h8 Ahi = *(const h8*)(whi + w5off + kwb);
                h8 Alo = *(const h8*)(wlo + w5off + kwb);
                av  = __builtin_amdgcn_mfma_f32_16x16x32_f16(Ahi, Bvh, av,  0, 0, 0);
                av  = __builtin_amdgcn_mfma_f32_16x16x32_f16(Ahi, Bvl, av,  0, 0, 0);
                av  = __builtin_amdgcn_mfma_f32_16x16x32_f16(Alo, Bvh, av,  0, 0, 0);
                ad  = __builtin_amdgcn_mfma_f32_16x16x32_f16(Ahi, Bdh, ad,  0, 0, 0);
                add = __builtin_amdgcn_mfma_f32_16x16x32_f16(Ahi, Bdd, add, 0, 0, 0);
            }
        }
        __syncthreads();   // planes dead after this point; overlay Fm/Um
        if (act) {
            int o0 = mtw * 16 + kg * 4;
            f4 bi = *(const f4*)(biasP + BP5 + o0);
            int sc = colS + 16 * g;
            float xv = xs[sc];
            float xm = xv * xv - 1.0f;
#pragma unroll
            for (int r = 0; r < 4; ++r) {
                int q = o0 + r;
                if (q < Q) {
                    float gv  = av[r] + bi[r];
                    float gd  = ad[r];
                    float gdd = add[r];
                    float U   = -1.0f + xm * gv;
                    float Uxx = 2.0f * gv + 4.0f * xv * gd + xm * gdd;
                    float Fv  = 5.0f * U * U * U - 5.0f * U - 0.0005f * Uxx;
                    Fm[sc * 104 + q] = Fv;
                    Um[sc * 104 + q] = U;
                }
            }
        }
        __syncthreads();
    }

    // ---- tail: U0 = U + DT*F@A^T ; U1 = U0 - DT*(F@bvec^T) (fp32 vector) ----
    {
        int qc = tid & 31;          // candidate q (and q+32, q+64, q+96)
        int ss = tid >> 5;          // sample 0..31
        float accq[4] = {0.f, 0.f, 0.f, 0.f};
        float cb = 0.f;
        const float* Fr = Fm + ss * 104;
#pragma unroll 5
        for (int j = 0; j < Q; j += 4) {
            f4 f4v = *(const f4*)(Fr + j);
            f4 bv4 = *(const f4*)(bvec + j);
            cb += f4v[0]*bv4[0] + f4v[1]*bv4[1] + f4v[2]*bv4[2] + f4v[3]*bv4[3];
#pragma unroll
            for (int u = 0; u < 4; ++u) {
                int q   = qc + 32 * u;
                int qcl = q < Q ? q : Q - 1;
                f4 a4 = *(const f4*)(A + qcl * Q + j);
                accq[u] += f4v[0]*a4[0] + f4v[1]*a4[1] + f4v[2]*a4[2] + f4v[3]*a4[3];
            }
        }
        int sg = bid * BS + ss;
#pragma unroll
        for (int u = 0; u < 4; ++u) {
            int q = qc + 32 * u;
            if (q < Q) {
                float U0 = Um[ss * 104 + q] + DTC * accq[u];
                float U1 = U0 - DTC * cb;
                out[sg * Q + q] = U0;
                out[NSAMP * Q + sg * Q + q] = U1;
            }
        }
    }
}

extern "C" void kernel_launch(void* const* d_in, const int* in_sizes, int n_in,
                              void* d_out, int out_size, void* d_ws, size_t ws_size,
                              hipStream_t stream) {
    const float* W0 = (const float*)d_in[0];
    const float* b0 = (const float*)d_in[1];
    const float* W1 = (const float*)d_in[2];
    const float* b1 = (const float*)d_in[3];
    const float* W2 = (const float*)d_in[4];
    const float* b2 = (const float*)d_in[5];
    const float* W3 = (const float*)d_in[6];
    const float* b3 = (const float*)d_in[7];
    const float* W4 = (const float*)d_in[8];
    const float* b4 = (const float*)d_in[9];
    const float* W5 = (const float*)d_in[10];
    const float* b5 = (const float*)d_in[11];
    const float* x  = (const float*)d_in[12];
    const float* A  = (const float*)d_in[13];
    const float* bv = (const float*)d_in[14];
    float* out = (float*)d_out;

    _Float16* whi = (_Float16*)d_ws;
    float* biasP  = (float*)((char*)d_ws + WS_BIAS_BYTE_OFF);

    prepass<<<(SW + BPTOT + 255) / 256, 256, 0, stream>>>(
        W1, b1, W2, b2, W3, b3, W4, b4, W5, b5, whi, biasP);

    pinn_mfma<<<NSAMP / BS, THREADS, 0, stream>>>(
        W0, b0, x, A, bv, whi, biasP, out);
}

// Round 2
// 434.436 us; speedup vs baseline: 1.0925x; 1.0925x over previous
//
#include <hip/hip_runtime.h>
#include <hip/hip_bf16.h>

// PINN fused forward+jvp^2 via split-fp16 MFMA.
// R12: revert to R10 residency (BS=16, 512 thr, 66.5KB LDS, 2 blocks/CU).
// New: (1) explicit 1-ahead register staging of A-fragment global loads for
// NMT<=2 layers (L1/L2/L4/L5) so the ~300cy L2 latency hides under the
// previous kt's MFMAs instead of stalling post-barrier; (2) v-accumulator
// split (accva/accvb) halves the dependent MFMA chain per kt; (3) s_setprio
// around each kt's MFMA cluster (2 resident blocks = role diversity).
// L3 (NMT=4) keeps the inline-load form: staging would exceed the 128-VGPR
// 2-block occupancy cliff. Tilings are exact (MTILES==NWACT*NMT), guards
// removed.

#define NSAMP 65536
#define Q     100
#define DTC   0.8f
#define BS    16
#define THREADS 512
#define STR   520          // LDS plane stride (halves)

typedef _Float16 h8 __attribute__((ext_vector_type(8)));
typedef _Float16 h4 __attribute__((ext_vector_type(4)));
typedef float    f4 __attribute__((ext_vector_type(4)));

// ---- packed fragment-ready weight geometry (halves) ----
// per layer: MT * KT * 512 halves (frag = 64 lanes x 8 halves)
// L1: MT=4,  KT=1  ->   2048
// L2: MT=14, KT=2  ->  14336
// L3: MT=32, KT=7  -> 114688
// L4: MT=14, KT=16 -> 114688
// L5: MT=7,  KT=7  ->  25088
#define SW 270848
#define C1 0
#define C2 2048
#define C3 16384
#define C4 131072
#define C5 245760
#define BP1 0
#define BP2 64
#define BP3 288
#define BP4 800
#define BP5 1024
#define BPTOT 1136
#define WS_BIAS_BYTE_OFF (SW*2*2)

__device__ __forceinline__ float fast_tanh(float z) {
    float az = fabsf(z);
    float e  = __expf(-2.0f * az);
    float r  = __builtin_amdgcn_rcpf(1.0f + e);
    float t  = (1.0f - e) * r;
    return copysignf(t, z);
}

struct Split { _Float16 hi, lo; };
__device__ __forceinline__ Split split16(float v) {
    Split s;
    s.hi = (_Float16)v;
    s.lo = (_Float16)(v - (float)s.hi);
    return s;
}

// ---------------- pre-pass: split/pad/PACK weights + biases into d_ws ----------------
__global__ __launch_bounds__(256) void prepass(
    const float* __restrict__ W1, const float* __restrict__ b1,
    const float* __restrict__ W2, const float* __restrict__ b2,
    const float* __restrict__ W3, const float* __restrict__ b3,
    const float* __restrict__ W4, const float* __restrict__ b4,
    const float* __restrict__ W5, const float* __restrict__ b5,
    _Float16* __restrict__ whi, float* __restrict__ biasP)
{
    int idx = blockIdx.x * 256 + threadIdx.x;
    _Float16* wlo = whi + SW;
    if (idx < SW) {
        int base, KT, K, FOUT; const float* W;
        if      (idx < C2) { base=C1; KT=1;  K=20;  FOUT=50;  W=W1; }
        else if (idx < C3) { base=C2; KT=2;  K=50;  FOUT=200; W=W2; }
        else if (idx < C4) { base=C3; KT=7;  K=200; FOUT=500; W=W3; }
        else if (idx < C5) { base=C4; KT=16; K=500; FOUT=200; W=W4; }
        else               { base=C5; KT=7;  K=200; FOUT=100; W=W5; }
        int r    = idx - base;
        int frag = r >> 9;
        int f    = r & 511;
        int lane = f >> 3;
        int e    = f & 7;
        int colS = lane & 15;
        int kg   = lane >> 4;
        int mt   = frag / KT;
        int kt   = frag - mt * KT;
        int o = mt * 16 + colS;
        int k = kt * 32 + kg * 8 + e;
        float v = (o < FOUT && k < K) ? W[o * K + k] : 0.f;
        Split sp = split16(v);
        whi[idx] = sp.hi; wlo[idx] = sp.lo;
    } else if (idx < SW + BPTOT) {
        int b = idx - SW;
        const float* src; int FOUT; int o;
        if      (b < BP2)  { src=b1; FOUT=50;  o=b;        }
        else if (b < BP3)  { src=b2; FOUT=200; o=b-BP2;    }
        else if (b < BP4)  { src=b3; FOUT=500; o=b-BP3;    }
        else if (b < BP5)  { src=b4; FOUT=200; o=b-BP4;    }
        else               { src=b5; FOUT=100; o=b-BP5;    }
        biasP[b] = (o < FOUT) ? src[o] : 0.f;
    }
}

// ---------------- one MFMA layer ----------------
// Planes (LDS, stride STR halves): vhi, vlo (split v-state), dhi, ddh (fp16 d/dd).
// B-frag: lane l -> col = l&15 (sample), k0 = (l>>4)*8 + kt*32.
// A-frag: PACKED: base + (mt*KT + kt)*512 + lane*8  -> coalesced 1KB load.
// C/D: col(lane&15)=sample, row((lane>>4)*4+reg)=output neuron.
// Staged path (NMT<=2): A-frags for kt+1 loaded while kt's MFMAs run.
template<int KP, int MTILES, int NMT, int NWACT, int FOUT, bool TANH>
__device__ __forceinline__ void layer_mfma(
    const _Float16* __restrict__ whi, const _Float16* __restrict__ wlo,
    int wcoff, const float* __restrict__ biasP,
    _Float16* vhi, _Float16* vlo, _Float16* dhi, _Float16* ddh,
    int lane, int wv)
{
    constexpr int KT  = KP / 32;
    constexpr bool STG = (NMT <= 2);
    static_assert(MTILES == NMT * NWACT, "exact tiling expected");
    const int colS = lane & 15;
    const int kg   = lane >> 4;
    const bool act = (wv < NWACT);

    f4 accva[NMT], accvb[STG ? NMT : 1], accd[NMT], accdd[NMT];

    if (act) {
#pragma unroll
        for (int i = 0; i < NMT; ++i) {
            accva[i] = (f4){0.f, 0.f, 0.f, 0.f};
            accd[i]  = (f4){0.f, 0.f, 0.f, 0.f};
            accdd[i] = (f4){0.f, 0.f, 0.f, 0.f};
        }
        if constexpr (STG) {
#pragma unroll
            for (int i = 0; i < NMT; ++i)
                accvb[i] = (f4){0.f, 0.f, 0.f, 0.f};
        }

        const int boff = colS * STR + kg * 8;

        unsigned woff[NMT];
#pragma unroll
        for (int i = 0; i < NMT; ++i)
            woff[i] = (unsigned)(wcoff + ((wv + NWACT * i) * KT) * 512 + lane * 8);

        if constexpr (STG) {
            // ---- software-pipelined A-load path ----
            h8 Ah[NMT], Al[NMT], Ah2[NMT], Al2[NMT];
#pragma unroll
            for (int i = 0; i < NMT; ++i) {
                Ah[i] = *(const h8*)(whi + woff[i]);
                Al[i] = *(const h8*)(wlo + woff[i]);
            }
#pragma unroll 2
            for (int kt = 0; kt < KT; ++kt) {
                if (kt + 1 < KT) {
                    const int kwb = (kt + 1) * 512;
#pragma unroll
                    for (int i = 0; i < NMT; ++i) {
                        Ah2[i] = *(const h8*)(whi + woff[i] + kwb);
                        Al2[i] = *(const h8*)(wlo + woff[i] + kwb);
                    }
                }
                const int kb = kt * 32;
                h8 Bvh = *(const h8*)(vhi + boff + kb);
                h8 Bvl = *(const h8*)(vlo + boff + kb);
                h8 Bdh = *(const h8*)(dhi + boff + kb);
                h8 Bdd = *(const h8*)(ddh + boff + kb);
                __builtin_amdgcn_s_setprio(1);
#pragma unroll
                for (int i = 0; i < NMT; ++i) {
                    accva[i] = __builtin_amdgcn_mfma_f32_16x16x32_f16(Ah[i], Bvh, accva[i], 0, 0, 0);
                    accvb[i] = __builtin_amdgcn_mfma_f32_16x16x32_f16(Ah[i], Bvl, accvb[i], 0, 0, 0);
                    accvb[i] = __builtin_amdgcn_mfma_f32_16x16x32_f16(Al[i], Bvh, accvb[i], 0, 0, 0);
                    accd[i]  = __builtin_amdgcn_mfma_f32_16x16x32_f16(Ah[i], Bdh, accd[i],  0, 0, 0);
                    accdd[i] = __builtin_amdgcn_mfma_f32_16x16x32_f16(Ah[i], Bdd, accdd[i], 0, 0, 0);
                }
                __builtin_amdgcn_s_setprio(0);
                if (kt + 1 < KT) {
#pragma unroll
                    for (int i = 0; i < NMT; ++i) { Ah[i] = Ah2[i]; Al[i] = Al2[i]; }
                }
            }
        } else {
            // ---- inline-load path (L3: NMT=4, register-tight) ----
#pragma unroll 2
            for (int kt = 0; kt < KT; ++kt) {
                const int kb  = kt * 32;
                const int kwb = kt * 512;
                h8 Bvh = *(const h8*)(vhi + boff + kb);
                h8 Bvl = *(const h8*)(vlo + boff + kb);
                h8 Bdh = *(const h8*)(dhi + boff + kb);
                h8 Bdd = *(const h8*)(ddh + boff + kb);
                __builtin_amdgcn_s_setprio(1);
#pragma unroll
                for (int i = 0; i < NMT; ++i) {
                    h8 Ahi = *(const h8*)(whi + woff[i] + kwb);
                    h8 Alo = *(const h8*)(wlo + woff[i] + kwb);
                    accva[i] = __builtin_amdgcn_mfma_f32_16x16x32_f16(Ahi, Bvh, accva[i], 0, 0, 0);
                    accva[i] = __builtin_amdgcn_mfma_f32_16x16x32_f16(Ahi, Bvl, accva[i], 0, 0, 0);
                    accva[i] = __builtin_amdgcn_mfma_f32_16x16x32_f16(Alo, Bvh, accva[i], 0, 0, 0);
                    accd[i]  = __builtin_amdgcn_mfma_f32_16x16x32_f16(Ahi, Bdh, accd[i],  0, 0, 0);
                    accdd[i] = __builtin_amdgcn_mfma_f32_16x16x32_f16(Ahi, Bdd, accdd[i], 0, 0, 0);
                }
                __builtin_amdgcn_s_setprio(0);
            }
        }
    }
    __syncthreads();   // all reads of planes complete before in-place overwrite

    if (act) {
#pragma unroll
        for (int i = 0; i < NMT; ++i) {
            int mt = wv + NWACT * i;
            int o0 = mt * 16 + kg * 4;
            f4 bi = *(const f4*)(biasP + o0);
            h4 pvh, pvl, pdh, pdd;
#pragma unroll
            for (int r = 0; r < 4; ++r) {
                float zv;
                if constexpr (STG) zv = accva[i][r] + accvb[i][r] + bi[r];
                else               zv = accva[i][r] + bi[r];
                float zd  = accd[i][r];
                float zdd = accdd[i][r];
                float ov, od, odd;
                if constexpr (TANH) {
                    float t  = fast_tanh(zv);
                    float s2 = 1.0f - t * t;
                    ov  = t;
                    od  = s2 * zd;
                    odd = s2 * zdd - 2.0f * t * s2 * zd * zd;
                } else {
                    ov = zv; od = zd; odd = zdd;
                }
                if (o0 + r >= FOUT) { ov = 0.f; od = 0.f; odd = 0.f; }
                Split sv = split16(ov);
                pvh[r] = sv.hi; pvl[r] = sv.lo;
                pdh[r] = (_Float16)od;
                pdd[r] = (_Float16)odd;
            }
            int off = colS * STR + o0;
            *(h4*)(vhi + off) = pvh;
            *(h4*)(vlo + off) = pvl;
            *(h4*)(dhi + off) = pdh;
            *(h4*)(ddh + off) = pdd;
        }
    }
    __syncthreads();
}

// ---------------- main fused kernel ----------------
__global__ __launch_bounds__(THREADS, 4) void pinn_mfma(
    const float* __restrict__ W0, const float* __restrict__ b0,
    const float* __restrict__ x,  const float* __restrict__ A,
    const float* __restrict__ bvec,
    const _Float16* __restrict__ whi, const float* __restrict__ biasP,
    float* __restrict__ out)
{
    __shared__ __align__(16) _Float16 smem[4 * BS * STR];   // 66,560 B
    __shared__ float xs[BS];

    _Float16* vhi = smem + 0 * BS * STR;
    _Float16* vlo = smem + 1 * BS * STR;
    _Float16* dhi = smem + 2 * BS * STR;
    _Float16* ddh = smem + 3 * BS * STR;
    // Fm/Um overlay the plane space after the last MFMA layer's barrier
    float* Fm = (float*)smem;              // 16 x 104 floats
    float* Um = Fm + BS * 104;

    const int tid  = threadIdx.x;
    const int bid  = blockIdx.x;
    const int lane = tid & 63;
    const int wv   = tid >> 6;
    const _Float16* wlo = whi + SW;

    if (tid < BS) xs[tid] = x[bid * BS + tid];
    __syncthreads();

    // ---- layer 0: 1 -> 20, write padded-K (32) input planes ----
    {
        int s = tid >> 5;       // 0..15
        int k = tid & 31;       // 0..31
        float v0 = 0.f, v1 = 0.f, v2 = 0.f;
        if (k < 20) {
            float w  = W0[k];
            float z  = w * xs[s] + b0[k];
            float t  = fast_tanh(z);
            float s2 = 1.0f - t * t;
            v0 = t; v1 = s2 * w; v2 = -2.0f * t * s2 * w * w;
        }
        Split s0 = split16(v0);
        int off = s * STR + k;
        vhi[off] = s0.hi;           vlo[off] = s0.lo;
        dhi[off] = (_Float16)v1;    ddh[off] = (_Float16)v2;
    }
    __syncthreads();

    //          KP   MT NMT NWA FOUT
    layer_mfma< 32,  4, 1,  4,  50, true>(whi, wlo, C1, biasP + BP1, vhi, vlo, dhi, ddh, lane, wv);
    layer_mfma< 64, 14, 2,  7, 200, true>(whi, wlo, C2, biasP + BP2, vhi, vlo, dhi, ddh, lane, wv);
    layer_mfma<224, 32, 4,  8, 500, true>(whi, wlo, C3, biasP + BP3, vhi, vlo, dhi, ddh, lane, wv);
    layer_mfma<512, 14, 2,  7, 200, true>(whi, wlo, C4, biasP + BP4, vhi, vlo, dhi, ddh, lane, wv);

    // ---- layer 5: 200 -> 100 linear, epilogue -> U, Uxx, F (overlay) ----
    {
        constexpr int KT = 7;
        const int colS = lane & 15;
        const int kg   = lane >> 4;
        const bool act = (wv < 7);
        f4 ava = (f4){0.f,0.f,0.f,0.f}, avb = ava, ad = ava, add = ava;
        if (act) {
            const int boff = colS * STR + kg * 8;
            const unsigned w5off = (unsigned)(C5 + (wv * KT) * 512 + lane * 8);
            h8 Ah = *(const h8*)(whi + w5off);
            h8 Al = *(const h8*)(wlo + w5off);
            h8 Ah2, Al2;
#pragma unroll 2
            for (int kt = 0; kt < KT; ++kt) {
                if (kt + 1 < KT) {
                    const int kwb = (kt + 1) * 512;
                    Ah2 = *(const h8*)(whi + w5off + kwb);
                    Al2 = *(const h8*)(wlo + w5off + kwb);
                }
                const int kb = kt * 32;
                h8 Bvh = *(const h8*)(vhi + boff + kb);
                h8 Bvl = *(const h8*)(vlo + boff + kb);
                h8 Bdh = *(const h8*)(dhi + boff + kb);
                h8 Bdd = *(const h8*)(ddh + boff + kb);
                __builtin_amdgcn_s_setprio(1);
                ava = __builtin_amdgcn_mfma_f32_16x16x32_f16(Ah, Bvh, ava, 0, 0, 0);
                avb = __builtin_amdgcn_mfma_f32_16x16x32_f16(Ah, Bvl, avb, 0, 0, 0);
                avb = __builtin_amdgcn_mfma_f32_16x16x32_f16(Al, Bvh, avb, 0, 0, 0);
                ad  = __builtin_amdgcn_mfma_f32_16x16x32_f16(Ah, Bdh, ad,  0, 0, 0);
                add = __builtin_amdgcn_mfma_f32_16x16x32_f16(Ah, Bdd, add, 0, 0, 0);
                __builtin_amdgcn_s_setprio(0);
                if (kt + 1 < KT) { Ah = Ah2; Al = Al2; }
            }
        }
        __syncthreads();   // planes dead after this point; overlay Fm/Um
        if (act) {
            int o0 = wv * 16 + kg * 4;
            f4 bi = *(const f4*)(biasP + BP5 + o0);
            float xv = xs[colS];
            float xm = xv * xv - 1.0f;
#pragma unroll
            for (int r = 0; r < 4; ++r) {
                int q = o0 + r;
                if (q < Q) {
                    float gv  = ava[r] + avb[r] + bi[r];
                    float gd  = ad[r];
                    float gdd = add[r];
                    float U   = -1.0f + xm * gv;
                    float Uxx = 2.0f * gv + 4.0f * xv * gd + xm * gdd;
                    float Fv  = 5.0f * U * U * U - 5.0f * U - 0.0005f * Uxx;
                    Fm[colS * 104 + q] = Fv;
                    Um[colS * 104 + q] = U;
                }
            }
        }
        __syncthreads();
    }

    // ---- tail: U0 = U + DT*F@A^T ; U1 = U0 - DT*(F@bvec^T) (fp32 vector) ----
    {
        int qc = tid & 31;          // candidate q (and q+32, q+64, q+96)
        int ss = tid >> 5;          // sample 0..15
        float accq[4] = {0.f, 0.f, 0.f, 0.f};
        float cb = 0.f;
        const float* Fr = Fm + ss * 104;
#pragma unroll 5
        for (int j = 0; j < Q; j += 4) {
            f4 f4v = *(const f4*)(Fr + j);
            f4 bv4 = *(const f4*)(bvec + j);
            cb += f4v[0]*bv4[0] + f4v[1]*bv4[1] + f4v[2]*bv4[2] + f4v[3]*bv4[3];
#pragma unroll
            for (int u = 0; u < 4; ++u) {
                int q   = qc + 32 * u;
                int qcl = q < Q ? q : Q - 1;
                f4 a4 = *(const f4*)(A + qcl * Q + j);
                accq[u] += f4v[0]*a4[0] + f4v[1]*a4[1] + f4v[2]*a4[2] + f4v[3]*a4[3];
            }
        }
        int sg = bid * BS + ss;
#pragma unroll
        for (int u = 0; u < 4; ++u) {
            int q = qc + 32 * u;
            if (q < Q) {
                float U0 = Um[ss * 104 + q] + DTC * accq[u];
                float U1 = U0 - DTC * cb;
                out[sg * Q + q] = U0;
                out[NSAMP * Q + sg * Q + q] = U1;
            }
        }
    }
}

extern "C" void kernel_launch(void* const* d_in, const int* in_sizes, int n_in,
                              void* d_out, int out_size, void* d_ws, size_t ws_size,
                              hipStream_t stream) {
    const float* W0 = (const float*)d_in[0];
    const float* b0 = (const float*)d_in[1];
    const float* W1 = (const float*)d_in[2];
    const float* b1 = (const float*)d_in[3];
    const float* W2 = (const float*)d_in[4];
    const float* b2 = (const float*)d_in[5];
    const float* W3 = (const float*)d_in[6];
    const float* b3 = (const float*)d_in[7];
    const float* W4 = (const float*)d_in[8];
    const float* b4 = (const float*)d_in[9];
    const float* W5 = (const float*)d_in[10];
    const float* b5 = (const float*)d_in[11];
    const float* x  = (const float*)d_in[12];
    const float* A  = (const float*)d_in[13];
    const float* bv = (const float*)d_in[14];
    float* out = (float*)d_out;

    _Float16* whi = (_Float16*)d_ws;
    float* biasP  = (float*)((char*)d_ws + WS_BIAS_BYTE_OFF);

    prepass<<<(SW + BPTOT + 255) / 256, 256, 0, stream>>>(
        W1, b1, W2, b2, W3, b3, W4, b4, W5, b5, whi, biasP);

    pinn_mfma<<<NSAMP / BS, THREADS, 0, stream>>>(
        W0, b0, x, A, bv, whi, biasP, out);
}